// Round 17
// baseline (51.968 us; speedup 1.0000x reference)
//
#include <hip/hip_runtime.h>

// ws layout (float offsets)
#define WS_T    0      // 324 floats: trig-basis tensor T[81][4]
#define WS_HQ   512    // 7840: hwq[k][pos] as float4
#define WS_WA   8352   // 1960: wavg[k][pos]
#define WS_H4   10312  // 1960: hz4[k][p4] as float4
#define WS_H8   12272  // 360:  hz8[k][p8] as float4
#define WS_C10  12632  // 10:   per-class constant

typedef float f32x4 __attribute__((ext_vector_type(4)));

__device__ __forceinline__ f32x4 vfma_s(const f32x4 a, const float s, const f32x4 c) {
  const f32x4 sv = {s, s, s, s};
  return __builtin_elementwise_fma(a, sv, c);   // -> v_pk_fma_f32 pairs
}
__device__ __forceinline__ f32x4 vfma_v(const f32x4 a, const f32x4 b, const f32x4 c) {
  return __builtin_elementwise_fma(a, b, c);
}
__device__ __forceinline__ float vsum4(const f32x4 a) {
  return a.x + a.y + a.z + a.w;
}

// ---------------------------------------------------------------------------
// Prep kernel, grid = 11 blocks (validated R16: parallel block 10).
// ---------------------------------------------------------------------------
__global__ __launch_bounds__(256) void prep_kernel(
    const float* __restrict__ qp, const float* __restrict__ hw,
    const float* __restrict__ res_w, const float* __restrict__ res_b,
    const float* __restrict__ hb, float* __restrict__ ws) {
  __shared__ float row[2352];
  __shared__ float cred[4];
  __shared__ float Sr[16][16];
  __shared__ float Si[16][16];
  __shared__ float csc[36], css[36];
  __shared__ float Afs[256][4];
  const int t = threadIdx.x;

  if (blockIdx.x < 10) {
    const int k = blockIdx.x;
    for (int i = t; i < 2352; i += 256) row[i] = hw[k * 2352 + i];
    __syncthreads();
    float cpart = 0.f;
    if (t < 196) {
      const int b12 = t * 12;
      float4 h = {row[b12], row[b12 + 1], row[b12 + 2], row[b12 + 3]};
      ((float4*)(ws + WS_HQ))[k * 196 + t] = h;
      float wa = 0.f;
#pragma unroll
      for (int c = 0; c < 4; ++c) {
        const float s3 = row[b12 + c] + row[b12 + 4 + c] + row[b12 + 8 + c];
        wa += res_w[c] * s3;
        cpart += res_b[c] * s3;
      }
      ws[WS_WA + k * 196 + t] = wa;
    }
    if (t < 49) {
      const int i4 = t / 7, j4 = t % 7;
      float4 s = {0.f, 0.f, 0.f, 0.f};
#pragma unroll
      for (int di = 0; di < 2; ++di)
#pragma unroll
        for (int dj = 0; dj < 2; ++dj) {
          const int pos = (2 * i4 + di) * 14 + 2 * j4 + dj;
          s.x += row[pos * 12 + 4]; s.y += row[pos * 12 + 5];
          s.z += row[pos * 12 + 6]; s.w += row[pos * 12 + 7];
        }
      ((float4*)(ws + WS_H4))[k * 49 + t] = s;
    }
    if (t < 9) {
      const int i8 = t / 3, j8 = t % 3;
      const int pi0 = (i8 == 0) ? 0 : ((i8 == 1) ? 5 : 9);
      const int pi1 = (i8 == 0) ? 5 : ((i8 == 1) ? 9 : 14);
      const int pj0 = (j8 == 0) ? 0 : ((j8 == 1) ? 5 : 9);
      const int pj1 = (j8 == 0) ? 5 : ((j8 == 1) ? 9 : 14);
      float4 s = {0.f, 0.f, 0.f, 0.f};
      for (int pi = pi0; pi < pi1; ++pi)
        for (int pj = pj0; pj < pj1; ++pj) {
          const int pos = pi * 14 + pj;
          s.x += row[pos * 12 + 8]; s.y += row[pos * 12 + 9];
          s.z += row[pos * 12 + 10]; s.w += row[pos * 12 + 11];
        }
      ((float4*)(ws + WS_H8))[k * 9 + t] = s;
    }
#pragma unroll
    for (int off = 32; off > 0; off >>= 1) cpart += __shfl_xor(cpart, off);
    if ((t & 63) == 0) cred[t >> 6] = cpart;
    __syncthreads();
    if (t == 0) ws[WS_C10 + k] = hb[k] + cred[0] + cred[1] + cred[2] + cred[3];
    return;
  }

  // ---- block 10: quantum tensor T, 256 threads, barriered ----
  if (t < 36) {
    float th = 0.5f * qp[t];
    csc[t] = cosf(th);
    css[t] = sinf(th);
  }
  Sr[t >> 4][t & 15] = ((t >> 4) == (t & 15)) ? 1.f : 0.f;
  Si[t >> 4][t & 15] = 0.f;
  __syncthreads();

  for (int l = 0; l < 3; ++l) {
    for (int q = 0; q < 4; ++q) {
      const int m = 8 >> q;
      if (t < 128) {  // 16 cols x 8 amplitude pairs, fused RX*RY*RZ
        const float cx = csc[l * 12 + q * 3 + 0], sx = css[l * 12 + q * 3 + 0];
        const float cy = csc[l * 12 + q * 3 + 1], sy = css[l * 12 + q * 3 + 1];
        const float cz = csc[l * 12 + q * 3 + 2], sz = css[l * 12 + q * 3 + 2];
        const int col = t >> 3, pp = t & 7;
        const int k = ((pp & ~(m - 1)) << 1) | (pp & (m - 1));
        const int k1 = k | m;
        float a0r = Sr[col][k],  a0i = Si[col][k];
        float a1r = Sr[col][k1], a1i = Si[col][k1];
        const float x0r = cx * a0r + sx * a1i, x0i = cx * a0i - sx * a1r;
        const float x1r = cx * a1r + sx * a0i, x1i = cx * a1i - sx * a0r;
        const float y0r = cy * x0r - sy * x1r, y0i = cy * x0i - sy * x1i;
        const float y1r = sy * x0r + cy * x1r, y1i = sy * x0i + cy * x1i;
        a0r = cz * y0r + sz * y0i;  a0i = cz * y0i - sz * y0r;
        a1r = cz * y1r - sz * y1i;  a1i = cz * y1i + sz * y1r;
        Sr[col][k] = a0r;  Si[col][k] = a0i;
        Sr[col][k1] = a1r; Si[col][k1] = a1i;
      }
      __syncthreads();
    }
    for (int e = 0; e < 4; ++e) {
      if (t < 64) {  // 16 cols x 4 swap pairs
        const int c2 = t >> 2, p2 = t & 3;
        const int mc = 8 >> e;
        const int mt = 8 >> ((e + 1) & 3);
        const int rest = 15 & ~(mc | mt);
        const int rl = rest & (-rest);
        const int rh = rest ^ rl;
        const int k = mc | ((p2 & 1) ? rl : 0) | ((p2 & 2) ? rh : 0);
        const int k1 = k | mt;
        float tr = Sr[c2][k]; Sr[c2][k] = Sr[c2][k1]; Sr[c2][k1] = tr;
        float ti = Si[c2][k]; Si[c2][k] = Si[c2][k1]; Si[c2][k1] = ti;
      }
      __syncthreads();
    }
  }

  // A_q[i][j]: one entry per thread (single pass)
  {
    const int i = t >> 4, j = t & 15;
    float a0 = 0.f, a1 = 0.f, a2 = 0.f, a3 = 0.f;
    for (int k = 0; k < 16; ++k) {
      float pr = Sr[i][k] * Sr[j][k] + Si[i][k] * Si[j][k];
      a0 += (k & 8) ? -pr : pr;
      a1 += (k & 4) ? -pr : pr;
      a2 += (k & 2) ? -pr : pr;
      a3 += (k & 1) ? -pr : pr;
    }
    Afs[t][0] = a0; Afs[t][1] = a1; Afs[t][2] = a2; Afs[t][3] = a3;
  }
  __syncthreads();

  // T: 324 outputs over 2 passes of 256 threads
  for (int o = t; o < 324; o += 256) {
    const int mi = o >> 2, q = o & 3;
    const int m0 = mi / 27, m1 = (mi / 9) % 3, m2 = (mi / 3) % 3, m3 = mi % 3;
    const int mm[4] = {m0, m1, m2, m3};
    float acc = 0.f;
    for (int c = 0; c < 16; ++c) {
      int ii = 0, jj = 0; float sg = 1.f;
      for (int qb = 0; qb < 4; ++qb) {
        const int cb = (c >> qb) & 1, bit = 8 >> qb, mq = mm[qb];
        if (mq == 2) { if (cb) ii |= bit; else jj |= bit; }
        else if (cb) { ii |= bit; jj |= bit; if (mq == 1) sg = -sg; }
      }
      acc += sg * Afs[ii * 16 + jj][q];
    }
    ws[WS_T + mi * 4 + q] = acc * 0.0625f;
  }
}

// ---------------------------------------------------------------------------
// Main kernel: R16 structure; g-loop now FULLY UNROLLED (compile-time T4
// offsets -> scalar s_load batches, no loop carry). Slot loop stays unroll 1
// (the register governor).
// ---------------------------------------------------------------------------
__global__ __launch_bounds__(256, 5) void qmain_kernel(
    const float* __restrict__ x, const f32x4* __restrict__ T4,
    const f32x4* __restrict__ HQ4, const float* __restrict__ WA,
    const f32x4* __restrict__ H44, const f32x4* __restrict__ H84,
    const float* __restrict__ C10,
    const float* __restrict__ dw4_w, const float* __restrict__ dw4_b,
    const float* __restrict__ pw4_w, const float* __restrict__ pw4_b,
    const float* __restrict__ dw8_w, const float* __restrict__ dw8_b,
    const float* __restrict__ pw8_w, const float* __restrict__ pw8_b,
    float* __restrict__ out, const int B) {
  __shared__ __align__(16) float xs[2 * 792];
  __shared__ float accw[4][10];
  const int t = threadIdx.x;
  const int w = t >> 6, lane = t & 63;
  const int il = w >> 1, pw = w & 1;
  const int img = blockIdx.x * 2 + il;
  float* xw = xs + il * 792;
  const f32x4* xw4 = (const f32x4*)xw;
  const bool ok = (img < B);

  if (ok) {
    const float4* xg = (const float4*)(x + img * 784);
    const int i0 = pw * 98 + lane;
    ((float4*)xw)[i0] = xg[i0];
    if (lane < 34) {
      const int i1 = pw * 98 + 64 + lane;
      ((float4*)xw)[i1] = xg[i1];
    }
  }

  float acc[10];
#pragma unroll
  for (int k = 0; k < 10; ++k) acc[k] = 0.f;

  // ---- quantum: 2 slots, serial (lean live set) ----
  if (ok && lane < 49) {
#pragma unroll 1
    for (int s = 0; s < 2; ++s) {
      const int p = 98 * pw + 49 * s + lane;
      const int base = 56 * (p / 14) + 2 * (p % 14);
      const float2 a01 = *(const float2*)(xw + base);
      const float2 a23 = *(const float2*)(xw + base + 28);
      float c0, s0, c1, s1, c2, s2, c3, s3;
      __sincosf(a01.x, &s0, &c0);
      __sincosf(a01.y, &s1, &c1);
      __sincosf(a23.x, &s2, &c2);
      __sincosf(a23.y, &s3, &c3);
      const float w01[9] = {1.f, c1, s1, c0, c0 * c1, c0 * s1, s0, s0 * c1, s0 * s1};
      f32x4 e = {0.f, 0.f, 0.f, 0.f};
#pragma unroll
      for (int g = 0; g < 9; ++g) {
        const f32x4 t0 = T4[g * 9 + 0], t1 = T4[g * 9 + 1], t2 = T4[g * 9 + 2];
        const f32x4 t3 = T4[g * 9 + 3], t4 = T4[g * 9 + 4], t5 = T4[g * 9 + 5];
        const f32x4 t6 = T4[g * 9 + 6], t7 = T4[g * 9 + 7], t8 = T4[g * 9 + 8];
        const f32x4 u0 = vfma_s(t2, s3, vfma_s(t1, c3, t0));
        const f32x4 u1 = vfma_s(t5, s3, vfma_s(t4, c3, t3));
        const f32x4 u2 = vfma_s(t8, s3, vfma_s(t7, c3, t6));
        const f32x4 inner = vfma_s(u2, s2, vfma_s(u1, c2, u0));
        e = vfma_s(inner, w01[g], e);
      }
      const float av = 0.25f * (a01.x + a01.y + a23.x + a23.y);
#pragma unroll
      for (int k = 0; k < 10; ++k) {
        const f32x4 h = HQ4[k * 196 + p];
        acc[k] += fmaf(h.x, e.x, fmaf(h.y, e.y,
                  fmaf(h.z, e.z, fmaf(h.w, e.w, WA[k * 196 + p] * av))));
      }
    }
  }
  __syncthreads();  // full image staged (feats span both halves)

  if (ok) {
    if (pw == 0) {
      if (lane < 49) {
        // ---- feat4 ----
        const int u = lane;
        const int i = u / 7, j = u % 7;
        const f32x4* w44 = (const f32x4*)dw4_w;
        f32x4 q0 = {0.f, 0.f, 0.f, 0.f}, q1 = q0, q2 = q0, q3 = q0;
#pragma unroll
        for (int uu = 0; uu < 4; ++uu) {
          const f32x4 xa = xw4[(4 * i + uu) * 7 + j];
          q0 = vfma_v(w44[0 + uu], xa, q0);
          q1 = vfma_v(w44[4 + uu], xa, q1);
          q2 = vfma_v(w44[8 + uu], xa, q2);
          q3 = vfma_v(w44[12 + uu], xa, q3);
        }
        const float y0 = vsum4(q0) + dw4_b[0];
        const float y1 = vsum4(q1) + dw4_b[1];
        const float y2 = vsum4(q2) + dw4_b[2];
        const float y3 = vsum4(q3) + dw4_b[3];
        float z[4];
#pragma unroll
        for (int o = 0; o < 4; ++o) {
          float zz = pw4_b[o];
          zz = fmaf(pw4_w[o * 4 + 0], y0, zz);
          zz = fmaf(pw4_w[o * 4 + 1], y1, zz);
          zz = fmaf(pw4_w[o * 4 + 2], y2, zz);
          zz = fmaf(pw4_w[o * 4 + 3], y3, zz);
          z[o] = fmaxf(zz, 0.f);
        }
#pragma unroll
        for (int k = 0; k < 10; ++k) {
          const f32x4 h = H44[k * 49 + u];
          acc[k] += fmaf(h.x, z[0], fmaf(h.y, z[1], fmaf(h.z, z[2], h.w * z[3])));
        }
      }
    } else {
      if (lane < 9) {
        // ---- feat8 ----
        const int pos = lane;
        const int i8 = pos / 3, j8 = pos % 3;
        const f32x4* w84 = (const f32x4*)dw8_w;
        f32x4 e0 = {0.f, 0.f, 0.f, 0.f}, e1 = e0, e2 = e0, e3 = e0;
#pragma unroll
        for (int uu = 0; uu < 8; ++uu) {
          const f32x4 xa = xw4[(8 * i8 + uu) * 7 + 2 * j8];
          const f32x4 xb = xw4[(8 * i8 + uu) * 7 + 2 * j8 + 1];
          e0 = vfma_v(w84[0 + uu * 2], xa, e0);
          e0 = vfma_v(w84[1 + uu * 2], xb, e0);
          e1 = vfma_v(w84[16 + uu * 2], xa, e1);
          e1 = vfma_v(w84[17 + uu * 2], xb, e1);
          e2 = vfma_v(w84[32 + uu * 2], xa, e2);
          e2 = vfma_v(w84[33 + uu * 2], xb, e2);
          e3 = vfma_v(w84[48 + uu * 2], xa, e3);
          e3 = vfma_v(w84[49 + uu * 2], xb, e3);
        }
        const float d0 = vsum4(e0) + dw8_b[0];
        const float d1 = vsum4(e1) + dw8_b[1];
        const float d2 = vsum4(e2) + dw8_b[2];
        const float d3 = vsum4(e3) + dw8_b[3];
        float z[4];
#pragma unroll
        for (int o = 0; o < 4; ++o) {
          float zz = pw8_b[o];
          zz = fmaf(pw8_w[o * 4 + 0], d0, zz);
          zz = fmaf(pw8_w[o * 4 + 1], d1, zz);
          zz = fmaf(pw8_w[o * 4 + 2], d2, zz);
          zz = fmaf(pw8_w[o * 4 + 3], d3, zz);
          z[o] = fmaxf(zz, 0.f);
        }
#pragma unroll
        for (int k = 0; k < 10; ++k) {
          const f32x4 h = H84[k * 9 + pos];
          acc[k] += fmaf(h.x, z[0], fmaf(h.y, z[1], fmaf(h.z, z[2], h.w * z[3])));
        }
      }
    }
  }

  // ---- per-wave butterfly reduction ----
#pragma unroll
  for (int k = 0; k < 10; ++k) {
    float v = acc[k];
    v += __shfl_xor(v, 1);
    v += __shfl_xor(v, 2);
    v += __shfl_xor(v, 4);
    v += __shfl_xor(v, 8);
    v += __shfl_xor(v, 16);
    v += __shfl_xor(v, 32);
    acc[k] = v;
  }
  {
    float v = acc[0];
#pragma unroll
    for (int k = 1; k < 10; ++k)
      if (lane == k) v = acc[k];
    if (lane < 10) accw[w][lane] = v;
  }
  __syncthreads();

  // ---- pairwise combine + log-softmax (even waves) ----
  if (pw == 0 && ok) {
    float lg = -1e30f;
    if (lane < 10) lg = accw[w][lane] + accw[w + 1][lane] + C10[lane];
    float mx = lg;
    mx = fmaxf(mx, __shfl_xor(mx, 1));
    mx = fmaxf(mx, __shfl_xor(mx, 2));
    mx = fmaxf(mx, __shfl_xor(mx, 4));
    mx = fmaxf(mx, __shfl_xor(mx, 8));
    float ex = (lane < 10) ? __expf(lg - mx) : 0.f;
    ex += __shfl_xor(ex, 1);
    ex += __shfl_xor(ex, 2);
    ex += __shfl_xor(ex, 4);
    ex += __shfl_xor(ex, 8);
    if (lane < 10) out[img * 10 + lane] = lg - mx - __logf(ex);
  }
}

extern "C" void kernel_launch(void* const* d_in, const int* in_sizes, int n_in,
                              void* d_out, int out_size, void* d_ws, size_t ws_size,
                              hipStream_t stream) {
  const float* x      = (const float*)d_in[0];
  const float* qp     = (const float*)d_in[1];
  const float* dw4_w  = (const float*)d_in[2];
  const float* dw4_b  = (const float*)d_in[3];
  const float* pw4_w  = (const float*)d_in[4];
  const float* pw4_b  = (const float*)d_in[5];
  const float* dw8_w  = (const float*)d_in[6];
  const float* dw8_b  = (const float*)d_in[7];
  const float* pw8_w  = (const float*)d_in[8];
  const float* pw8_b  = (const float*)d_in[9];
  const float* res_w  = (const float*)d_in[10];
  const float* res_b  = (const float*)d_in[11];
  const float* head_w = (const float*)d_in[12];
  const float* head_b = (const float*)d_in[13];
  float* out = (float*)d_out;
  float* ws = (float*)d_ws;
  const int B = in_sizes[0] / 784;

  hipLaunchKernelGGL(prep_kernel, dim3(11), dim3(256), 0, stream,
                     qp, head_w, res_w, res_b, head_b, ws);
  hipLaunchKernelGGL(qmain_kernel, dim3((B + 1) / 2), dim3(256), 0, stream,
                     x, (const f32x4*)(ws + WS_T),
                     (const f32x4*)(ws + WS_HQ), ws + WS_WA,
                     (const f32x4*)(ws + WS_H4), (const f32x4*)(ws + WS_H8),
                     ws + WS_C10,
                     dw4_w, dw4_b, pw4_w, pw4_b, dw8_w, dw8_b, pw8_w, pw8_b,
                     out, B);
}

// Round 18
// 30.021 us; speedup vs baseline: 1.7311x; 1.7311x over previous
//
#include <hip/hip_runtime.h>

// ws layout (float offsets)
#define WS_T    0      // 324 floats: trig-basis tensor T[81][4]
#define WS_HQ   512    // 7840: hwq[k][pos] as float4
#define WS_WA   8352   // 1960: wavg[k][pos]
#define WS_H4   10312  // 1960: hz4[k][p4] as float4
#define WS_H8   12272  // 360:  hz8[k][p8] as float4
#define WS_C10  12632  // 10:   per-class constant

typedef float f32x4 __attribute__((ext_vector_type(4)));

__device__ __forceinline__ f32x4 vfma_s(const f32x4 a, const float s, const f32x4 c) {
  const f32x4 sv = {s, s, s, s};
  return __builtin_elementwise_fma(a, sv, c);   // -> v_pk_fma_f32 pairs
}
__device__ __forceinline__ f32x4 vfma_v(const f32x4 a, const f32x4 b, const f32x4 c) {
  return __builtin_elementwise_fma(a, b, c);
}
__device__ __forceinline__ float vsum4(const f32x4 a) {
  return a.x + a.y + a.z + a.w;
}

// ---------------------------------------------------------------------------
// Prep kernel, grid = 11 blocks (validated R16: parallel block 10).
// ---------------------------------------------------------------------------
__global__ __launch_bounds__(256) void prep_kernel(
    const float* __restrict__ qp, const float* __restrict__ hw,
    const float* __restrict__ res_w, const float* __restrict__ res_b,
    const float* __restrict__ hb, float* __restrict__ ws) {
  __shared__ float row[2352];
  __shared__ float cred[4];
  __shared__ float Sr[16][16];
  __shared__ float Si[16][16];
  __shared__ float csc[36], css[36];
  __shared__ float Afs[256][4];
  const int t = threadIdx.x;

  if (blockIdx.x < 10) {
    const int k = blockIdx.x;
    for (int i = t; i < 2352; i += 256) row[i] = hw[k * 2352 + i];
    __syncthreads();
    float cpart = 0.f;
    if (t < 196) {
      const int b12 = t * 12;
      float4 h = {row[b12], row[b12 + 1], row[b12 + 2], row[b12 + 3]};
      ((float4*)(ws + WS_HQ))[k * 196 + t] = h;
      float wa = 0.f;
#pragma unroll
      for (int c = 0; c < 4; ++c) {
        const float s3 = row[b12 + c] + row[b12 + 4 + c] + row[b12 + 8 + c];
        wa += res_w[c] * s3;
        cpart += res_b[c] * s3;
      }
      ws[WS_WA + k * 196 + t] = wa;
    }
    if (t < 49) {
      const int i4 = t / 7, j4 = t % 7;
      float4 s = {0.f, 0.f, 0.f, 0.f};
#pragma unroll
      for (int di = 0; di < 2; ++di)
#pragma unroll
        for (int dj = 0; dj < 2; ++dj) {
          const int pos = (2 * i4 + di) * 14 + 2 * j4 + dj;
          s.x += row[pos * 12 + 4]; s.y += row[pos * 12 + 5];
          s.z += row[pos * 12 + 6]; s.w += row[pos * 12 + 7];
        }
      ((float4*)(ws + WS_H4))[k * 49 + t] = s;
    }
    if (t < 9) {
      const int i8 = t / 3, j8 = t % 3;
      const int pi0 = (i8 == 0) ? 0 : ((i8 == 1) ? 5 : 9);
      const int pi1 = (i8 == 0) ? 5 : ((i8 == 1) ? 9 : 14);
      const int pj0 = (j8 == 0) ? 0 : ((j8 == 1) ? 5 : 9);
      const int pj1 = (j8 == 0) ? 5 : ((j8 == 1) ? 9 : 14);
      float4 s = {0.f, 0.f, 0.f, 0.f};
      for (int pi = pi0; pi < pi1; ++pi)
        for (int pj = pj0; pj < pj1; ++pj) {
          const int pos = pi * 14 + pj;
          s.x += row[pos * 12 + 8]; s.y += row[pos * 12 + 9];
          s.z += row[pos * 12 + 10]; s.w += row[pos * 12 + 11];
        }
      ((float4*)(ws + WS_H8))[k * 9 + t] = s;
    }
#pragma unroll
    for (int off = 32; off > 0; off >>= 1) cpart += __shfl_xor(cpart, off);
    if ((t & 63) == 0) cred[t >> 6] = cpart;
    __syncthreads();
    if (t == 0) ws[WS_C10 + k] = hb[k] + cred[0] + cred[1] + cred[2] + cred[3];
    return;
  }

  // ---- block 10: quantum tensor T, 256 threads, barriered ----
  if (t < 36) {
    float th = 0.5f * qp[t];
    csc[t] = cosf(th);
    css[t] = sinf(th);
  }
  Sr[t >> 4][t & 15] = ((t >> 4) == (t & 15)) ? 1.f : 0.f;
  Si[t >> 4][t & 15] = 0.f;
  __syncthreads();

  for (int l = 0; l < 3; ++l) {
    for (int q = 0; q < 4; ++q) {
      const int m = 8 >> q;
      if (t < 128) {  // 16 cols x 8 amplitude pairs, fused RX*RY*RZ
        const float cx = csc[l * 12 + q * 3 + 0], sx = css[l * 12 + q * 3 + 0];
        const float cy = csc[l * 12 + q * 3 + 1], sy = css[l * 12 + q * 3 + 1];
        const float cz = csc[l * 12 + q * 3 + 2], sz = css[l * 12 + q * 3 + 2];
        const int col = t >> 3, pp = t & 7;
        const int k = ((pp & ~(m - 1)) << 1) | (pp & (m - 1));
        const int k1 = k | m;
        float a0r = Sr[col][k],  a0i = Si[col][k];
        float a1r = Sr[col][k1], a1i = Si[col][k1];
        const float x0r = cx * a0r + sx * a1i, x0i = cx * a0i - sx * a1r;
        const float x1r = cx * a1r + sx * a0i, x1i = cx * a1i - sx * a0r;
        const float y0r = cy * x0r - sy * x1r, y0i = cy * x0i - sy * x1i;
        const float y1r = sy * x0r + cy * x1r, y1i = sy * x0i + cy * x1i;
        a0r = cz * y0r + sz * y0i;  a0i = cz * y0i - sz * y0r;
        a1r = cz * y1r - sz * y1i;  a1i = cz * y1i + sz * y1r;
        Sr[col][k] = a0r;  Si[col][k] = a0i;
        Sr[col][k1] = a1r; Si[col][k1] = a1i;
      }
      __syncthreads();
    }
    for (int e = 0; e < 4; ++e) {
      if (t < 64) {  // 16 cols x 4 swap pairs
        const int c2 = t >> 2, p2 = t & 3;
        const int mc = 8 >> e;
        const int mt = 8 >> ((e + 1) & 3);
        const int rest = 15 & ~(mc | mt);
        const int rl = rest & (-rest);
        const int rh = rest ^ rl;
        const int k = mc | ((p2 & 1) ? rl : 0) | ((p2 & 2) ? rh : 0);
        const int k1 = k | mt;
        float tr = Sr[c2][k]; Sr[c2][k] = Sr[c2][k1]; Sr[c2][k1] = tr;
        float ti = Si[c2][k]; Si[c2][k] = Si[c2][k1]; Si[c2][k1] = ti;
      }
      __syncthreads();
    }
  }

  // A_q[i][j]: one entry per thread (single pass)
  {
    const int i = t >> 4, j = t & 15;
    float a0 = 0.f, a1 = 0.f, a2 = 0.f, a3 = 0.f;
    for (int k = 0; k < 16; ++k) {
      float pr = Sr[i][k] * Sr[j][k] + Si[i][k] * Si[j][k];
      a0 += (k & 8) ? -pr : pr;
      a1 += (k & 4) ? -pr : pr;
      a2 += (k & 2) ? -pr : pr;
      a3 += (k & 1) ? -pr : pr;
    }
    Afs[t][0] = a0; Afs[t][1] = a1; Afs[t][2] = a2; Afs[t][3] = a3;
  }
  __syncthreads();

  // T: 324 outputs over 2 passes of 256 threads
  for (int o = t; o < 324; o += 256) {
    const int mi = o >> 2, q = o & 3;
    const int m0 = mi / 27, m1 = (mi / 9) % 3, m2 = (mi / 3) % 3, m3 = mi % 3;
    const int mm[4] = {m0, m1, m2, m3};
    float acc = 0.f;
    for (int c = 0; c < 16; ++c) {
      int ii = 0, jj = 0; float sg = 1.f;
      for (int qb = 0; qb < 4; ++qb) {
        const int cb = (c >> qb) & 1, bit = 8 >> qb, mq = mm[qb];
        if (mq == 2) { if (cb) ii |= bit; else jj |= bit; }
        else if (cb) { ii |= bit; jj |= bit; if (mq == 1) sg = -sg; }
      }
      acc += sg * Afs[ii * 16 + jj][q];
    }
    ws[WS_T + mi * 4 + q] = acc * 0.0625f;
  }
}

// ---------------------------------------------------------------------------
// Main kernel: R16 (best, validated): two waves/image, (256,5), serial
// 2-slot body with runtime g-loop (the register governor), packed-fp32
// contraction & feats.
// ---------------------------------------------------------------------------
__global__ __launch_bounds__(256, 5) void qmain_kernel(
    const float* __restrict__ x, const f32x4* __restrict__ T4,
    const f32x4* __restrict__ HQ4, const float* __restrict__ WA,
    const f32x4* __restrict__ H44, const f32x4* __restrict__ H84,
    const float* __restrict__ C10,
    const float* __restrict__ dw4_w, const float* __restrict__ dw4_b,
    const float* __restrict__ pw4_w, const float* __restrict__ pw4_b,
    const float* __restrict__ dw8_w, const float* __restrict__ dw8_b,
    const float* __restrict__ pw8_w, const float* __restrict__ pw8_b,
    float* __restrict__ out, const int B) {
  __shared__ __align__(16) float xs[2 * 792];
  __shared__ float accw[4][10];
  const int t = threadIdx.x;
  const int w = t >> 6, lane = t & 63;
  const int il = w >> 1, pw = w & 1;
  const int img = blockIdx.x * 2 + il;
  float* xw = xs + il * 792;
  const f32x4* xw4 = (const f32x4*)xw;
  const bool ok = (img < B);

  if (ok) {
    const float4* xg = (const float4*)(x + img * 784);
    const int i0 = pw * 98 + lane;
    ((float4*)xw)[i0] = xg[i0];
    if (lane < 34) {
      const int i1 = pw * 98 + 64 + lane;
      ((float4*)xw)[i1] = xg[i1];
    }
  }

  float acc[10];
#pragma unroll
  for (int k = 0; k < 10; ++k) acc[k] = 0.f;

  // ---- quantum: 2 slots, serial (lean live set; validated R11/R15) ----
  if (ok && lane < 49) {
#pragma unroll 1
    for (int s = 0; s < 2; ++s) {
      const int p = 98 * pw + 49 * s + lane;
      const int base = 56 * (p / 14) + 2 * (p % 14);
      const float2 a01 = *(const float2*)(xw + base);
      const float2 a23 = *(const float2*)(xw + base + 28);
      float c0, s0, c1, s1, c2, s2, c3, s3;
      __sincosf(a01.x, &s0, &c0);
      __sincosf(a01.y, &s1, &c1);
      __sincosf(a23.x, &s2, &c2);
      __sincosf(a23.y, &s3, &c3);
      const float w01[9] = {1.f, c1, s1, c0, c0 * c1, c0 * s1, s0, s0 * c1, s0 * s1};
      f32x4 e = {0.f, 0.f, 0.f, 0.f};
#pragma unroll 1
      for (int g = 0; g < 9; ++g) {
        const f32x4 t0 = T4[g * 9 + 0], t1 = T4[g * 9 + 1], t2 = T4[g * 9 + 2];
        const f32x4 t3 = T4[g * 9 + 3], t4 = T4[g * 9 + 4], t5 = T4[g * 9 + 5];
        const f32x4 t6 = T4[g * 9 + 6], t7 = T4[g * 9 + 7], t8 = T4[g * 9 + 8];
        const f32x4 u0 = vfma_s(t2, s3, vfma_s(t1, c3, t0));
        const f32x4 u1 = vfma_s(t5, s3, vfma_s(t4, c3, t3));
        const f32x4 u2 = vfma_s(t8, s3, vfma_s(t7, c3, t6));
        const f32x4 inner = vfma_s(u2, s2, vfma_s(u1, c2, u0));
        e = vfma_s(inner, w01[g], e);
      }
      const float av = 0.25f * (a01.x + a01.y + a23.x + a23.y);
#pragma unroll
      for (int k = 0; k < 10; ++k) {
        const f32x4 h = HQ4[k * 196 + p];
        acc[k] += fmaf(h.x, e.x, fmaf(h.y, e.y,
                  fmaf(h.z, e.z, fmaf(h.w, e.w, WA[k * 196 + p] * av))));
      }
    }
  }
  __syncthreads();  // full image staged (feats span both halves)

  if (ok) {
    if (pw == 0) {
      if (lane < 49) {
        // ---- feat4 ----
        const int u = lane;
        const int i = u / 7, j = u % 7;
        const f32x4* w44 = (const f32x4*)dw4_w;
        f32x4 q0 = {0.f, 0.f, 0.f, 0.f}, q1 = q0, q2 = q0, q3 = q0;
#pragma unroll
        for (int uu = 0; uu < 4; ++uu) {
          const f32x4 xa = xw4[(4 * i + uu) * 7 + j];
          q0 = vfma_v(w44[0 + uu], xa, q0);
          q1 = vfma_v(w44[4 + uu], xa, q1);
          q2 = vfma_v(w44[8 + uu], xa, q2);
          q3 = vfma_v(w44[12 + uu], xa, q3);
        }
        const float y0 = vsum4(q0) + dw4_b[0];
        const float y1 = vsum4(q1) + dw4_b[1];
        const float y2 = vsum4(q2) + dw4_b[2];
        const float y3 = vsum4(q3) + dw4_b[3];
        float z[4];
#pragma unroll
        for (int o = 0; o < 4; ++o) {
          float zz = pw4_b[o];
          zz = fmaf(pw4_w[o * 4 + 0], y0, zz);
          zz = fmaf(pw4_w[o * 4 + 1], y1, zz);
          zz = fmaf(pw4_w[o * 4 + 2], y2, zz);
          zz = fmaf(pw4_w[o * 4 + 3], y3, zz);
          z[o] = fmaxf(zz, 0.f);
        }
#pragma unroll
        for (int k = 0; k < 10; ++k) {
          const f32x4 h = H44[k * 49 + u];
          acc[k] += fmaf(h.x, z[0], fmaf(h.y, z[1], fmaf(h.z, z[2], h.w * z[3])));
        }
      }
    } else {
      if (lane < 9) {
        // ---- feat8 ----
        const int pos = lane;
        const int i8 = pos / 3, j8 = pos % 3;
        const f32x4* w84 = (const f32x4*)dw8_w;
        f32x4 e0 = {0.f, 0.f, 0.f, 0.f}, e1 = e0, e2 = e0, e3 = e0;
#pragma unroll
        for (int uu = 0; uu < 8; ++uu) {
          const f32x4 xa = xw4[(8 * i8 + uu) * 7 + 2 * j8];
          const f32x4 xb = xw4[(8 * i8 + uu) * 7 + 2 * j8 + 1];
          e0 = vfma_v(w84[0 + uu * 2], xa, e0);
          e0 = vfma_v(w84[1 + uu * 2], xb, e0);
          e1 = vfma_v(w84[16 + uu * 2], xa, e1);
          e1 = vfma_v(w84[17 + uu * 2], xb, e1);
          e2 = vfma_v(w84[32 + uu * 2], xa, e2);
          e2 = vfma_v(w84[33 + uu * 2], xb, e2);
          e3 = vfma_v(w84[48 + uu * 2], xa, e3);
          e3 = vfma_v(w84[49 + uu * 2], xb, e3);
        }
        const float d0 = vsum4(e0) + dw8_b[0];
        const float d1 = vsum4(e1) + dw8_b[1];
        const float d2 = vsum4(e2) + dw8_b[2];
        const float d3 = vsum4(e3) + dw8_b[3];
        float z[4];
#pragma unroll
        for (int o = 0; o < 4; ++o) {
          float zz = pw8_b[o];
          zz = fmaf(pw8_w[o * 4 + 0], d0, zz);
          zz = fmaf(pw8_w[o * 4 + 1], d1, zz);
          zz = fmaf(pw8_w[o * 4 + 2], d2, zz);
          zz = fmaf(pw8_w[o * 4 + 3], d3, zz);
          z[o] = fmaxf(zz, 0.f);
        }
#pragma unroll
        for (int k = 0; k < 10; ++k) {
          const f32x4 h = H84[k * 9 + pos];
          acc[k] += fmaf(h.x, z[0], fmaf(h.y, z[1], fmaf(h.z, z[2], h.w * z[3])));
        }
      }
    }
  }

  // ---- per-wave butterfly reduction ----
#pragma unroll
  for (int k = 0; k < 10; ++k) {
    float v = acc[k];
    v += __shfl_xor(v, 1);
    v += __shfl_xor(v, 2);
    v += __shfl_xor(v, 4);
    v += __shfl_xor(v, 8);
    v += __shfl_xor(v, 16);
    v += __shfl_xor(v, 32);
    acc[k] = v;
  }
  {
    float v = acc[0];
#pragma unroll
    for (int k = 1; k < 10; ++k)
      if (lane == k) v = acc[k];
    if (lane < 10) accw[w][lane] = v;
  }
  __syncthreads();

  // ---- pairwise combine + log-softmax (even waves) ----
  if (pw == 0 && ok) {
    float lg = -1e30f;
    if (lane < 10) lg = accw[w][lane] + accw[w + 1][lane] + C10[lane];
    float mx = lg;
    mx = fmaxf(mx, __shfl_xor(mx, 1));
    mx = fmaxf(mx, __shfl_xor(mx, 2));
    mx = fmaxf(mx, __shfl_xor(mx, 4));
    mx = fmaxf(mx, __shfl_xor(mx, 8));
    float ex = (lane < 10) ? __expf(lg - mx) : 0.f;
    ex += __shfl_xor(ex, 1);
    ex += __shfl_xor(ex, 2);
    ex += __shfl_xor(ex, 4);
    ex += __shfl_xor(ex, 8);
    if (lane < 10) out[img * 10 + lane] = lg - mx - __logf(ex);
  }
}

extern "C" void kernel_launch(void* const* d_in, const int* in_sizes, int n_in,
                              void* d_out, int out_size, void* d_ws, size_t ws_size,
                              hipStream_t stream) {
  const float* x      = (const float*)d_in[0];
  const float* qp     = (const float*)d_in[1];
  const float* dw4_w  = (const float*)d_in[2];
  const float* dw4_b  = (const float*)d_in[3];
  const float* pw4_w  = (const float*)d_in[4];
  const float* pw4_b  = (const float*)d_in[5];
  const float* dw8_w  = (const float*)d_in[6];
  const float* dw8_b  = (const float*)d_in[7];
  const float* pw8_w  = (const float*)d_in[8];
  const float* pw8_b  = (const float*)d_in[9];
  const float* res_w  = (const float*)d_in[10];
  const float* res_b  = (const float*)d_in[11];
  const float* head_w = (const float*)d_in[12];
  const float* head_b = (const float*)d_in[13];
  float* out = (float*)d_out;
  float* ws = (float*)d_ws;
  const int B = in_sizes[0] / 784;

  hipLaunchKernelGGL(prep_kernel, dim3(11), dim3(256), 0, stream,
                     qp, head_w, res_w, res_b, head_b, ws);
  hipLaunchKernelGGL(qmain_kernel, dim3((B + 1) / 2), dim3(256), 0, stream,
                     x, (const f32x4*)(ws + WS_T),
                     (const f32x4*)(ws + WS_HQ), ws + WS_WA,
                     (const f32x4*)(ws + WS_H4), (const f32x4*)(ws + WS_H8),
                     ws + WS_C10,
                     dw4_w, dw4_b, pw4_w, pw4_b, dw8_w, dw8_b, pw8_w, pw8_b,
                     out, B);
}